// Round 1
// baseline (9169.434 us; speedup 1.0000x reference)
//
#include <hip/hip_runtime.h>
#include <stdint.h>

#define B_ 16
#define T_ 64
#define IN_ 1024
#define R_ 4096
#define A_ 18
#define H_ 1024
#define NC_ 32
#define NK_ 32
#define LAT_ 1024
#define NB_ 8
#define BS_ 512
#define FULL_ 5120
#define GIN_ 5138
#define G3_ 1536
#define NG_ 12288   // NB_*G3_

#define FULLS0 0
#define RECS0 5242880            // B*T*FULL
#define POST0 9437184            // + B*T*R
#define PRIOR0 10485760          // + B*T*LAT

#define KS1 64   // posterior mlp layer1: K=5120, chunk 80
#define KC1 80
#define KS2 32   // posterior mlp layer2: K=1024, chunk 32
#define KC2 32
#define KSG 16   // GRU input GEMM (h part): K=4096, chunk 256
#define KCG 256
#define KSH 8    // GRU recurrent GEMM: K=512, chunk 64
#define KCH 64

// ---------------- threefry2x32 (JAX-exact) ----------------
__device__ __forceinline__ uint32_t rotl32(uint32_t v, int r){ return (v<<r)|(v>>(32-r)); }

__device__ __forceinline__ void tf2x32(uint32_t k0, uint32_t k1, uint32_t x0, uint32_t x1,
                                       uint32_t& o0, uint32_t& o1){
  uint32_t ks0=k0, ks1=k1, ks2=k0^k1^0x1BD11BDAu;
  x0+=ks0; x1+=ks1;
  x0+=x1; x1=rotl32(x1,13); x1^=x0;
  x0+=x1; x1=rotl32(x1,15); x1^=x0;
  x0+=x1; x1=rotl32(x1,26); x1^=x0;
  x0+=x1; x1=rotl32(x1, 6); x1^=x0;
  x0+=ks1; x1+=ks2+1u;
  x0+=x1; x1=rotl32(x1,17); x1^=x0;
  x0+=x1; x1=rotl32(x1,29); x1^=x0;
  x0+=x1; x1=rotl32(x1,16); x1^=x0;
  x0+=x1; x1=rotl32(x1,24); x1^=x0;
  x0+=ks2; x1+=ks0+2u;
  x0+=x1; x1=rotl32(x1,13); x1^=x0;
  x0+=x1; x1=rotl32(x1,15); x1^=x0;
  x0+=x1; x1=rotl32(x1,26); x1^=x0;
  x0+=x1; x1=rotl32(x1, 6); x1^=x0;
  x0+=ks0; x1+=ks1+3u;
  x0+=x1; x1=rotl32(x1,17); x1^=x0;
  x0+=x1; x1=rotl32(x1,29); x1^=x0;
  x0+=x1; x1=rotl32(x1,16); x1^=x0;
  x0+=x1; x1=rotl32(x1,24); x1^=x0;
  x0+=ks1; x1+=ks2+4u;
  x0+=x1; x1=rotl32(x1,13); x1^=x0;
  x0+=x1; x1=rotl32(x1,15); x1^=x0;
  x0+=x1; x1=rotl32(x1,26); x1^=x0;
  x0+=x1; x1=rotl32(x1, 6); x1^=x0;
  x0+=ks2; x1+=ks0+5u;
  o0=x0; o1=x1;
}

// Gumbel table for all (t, b, nc, nk). JAX "partitionable" threefry flavor
// (default in modern JAX): keys[t] = tf(key(1)=(0,1), (0,t));
// bits[i] = o0^o1 of tf(key_t, (0,i)); u = bitcast(0x3F800000|(bits>>9))-1.
__global__ __launch_bounds__(256) void gumbel_init(float* __restrict__ gum){
  int g = blockIdx.x*256 + threadIdx.x;     // 64 * 16384
  int t = g >> 14, i = g & 16383;
  uint32_t k0t, k1t, o0, o1;
  tf2x32(0u, 1u, 0u, (uint32_t)t, k0t, k1t);
  tf2x32(k0t, k1t, 0u, (uint32_t)i, o0, o1);
  uint32_t bits = o0 ^ o1;
  uint32_t fb = (bits >> 9) | 0x3f800000u;
  float f = __uint_as_float(fb) - 1.0f;
  const float tiny = 1.17549435e-38f;
  float u = fmaxf(tiny, f + tiny);
  gum[g] = -logf(-logf(u));
}

// ---------------- per-step kernels ----------------

// layer1 of posterior MLP: x = [h, obs_t] (16 x 5120) @ pw1 (5120 x 1024) -> partials
__global__ __launch_bounds__(256) void mlp1_gemv(const float* __restrict__ pw1,
    const float* __restrict__ h, const float* __restrict__ obs, int t,
    float* __restrict__ p1){
  int ct = blockIdx.x, ks = blockIdx.y, tid = threadIdx.x;
  int col = ct*512 + tid;
  int k0 = ks*KC1;
  __shared__ float xs[KC1*16];
  for (int i = tid; i < KC1*16; i += 256){
    int kk = i >> 4, m = i & 15;
    int k = k0 + kk;
    xs[i] = (k < R_) ? h[m*R_ + k] : obs[((m*T_)+t)*IN_ + (k - R_)];
  }
  __syncthreads();
  float a0[16], a1[16];
  #pragma unroll
  for (int m=0;m<16;m++){ a0[m]=0.f; a1[m]=0.f; }
  const float* w = pw1 + (size_t)k0*H_ + col;
  #pragma unroll 4
  for (int kk=0; kk<KC1; kk++){
    float w0 = w[0], w1 = w[256];
    w += H_;
    #pragma unroll
    for (int m=0;m<16;m++){
      float x = xs[kk*16+m];
      a0[m] = fmaf(x, w0, a0[m]);
      a1[m] = fmaf(x, w1, a1[m]);
    }
  }
  float* o = p1 + (size_t)ks*B_*H_ + col;
  #pragma unroll
  for (int m=0;m<16;m++){ o[(size_t)m*H_] = a0[m]; o[(size_t)m*H_ + 256] = a1[m]; }
}

// reduce partials + bias + silu -> hidden [16,1024]
__global__ __launch_bounds__(256) void mlp1_reduce(const float* __restrict__ p1,
    const float* __restrict__ pb1, float* __restrict__ hidden){
  int g = blockIdx.x*256 + threadIdx.x;   // 16384
  int b = g >> 10, c = g & 1023;
  float v = pb1[c];
  #pragma unroll 8
  for (int s=0;s<KS1;s++) v += p1[((size_t)s*B_ + b)*H_ + c];
  float sg = 1.f/(1.f + expf(-v));
  hidden[g] = v * sg;
}

// layer2: hidden (16x1024) @ pw2 (1024x1024) -> partials
__global__ __launch_bounds__(256) void mlp2_gemv(const float* __restrict__ pw2,
    const float* __restrict__ hidden, float* __restrict__ p2){
  int ct = blockIdx.x, ks = blockIdx.y, tid = threadIdx.x;
  int col = ct*512 + tid;
  int k0 = ks*KC2;
  __shared__ float xs[KC2*16];
  for (int i = tid; i < KC2*16; i += 256){
    int kk = i >> 4, m = i & 15;
    xs[i] = hidden[m*H_ + k0 + kk];
  }
  __syncthreads();
  float a0[16], a1[16];
  #pragma unroll
  for (int m=0;m<16;m++){ a0[m]=0.f; a1[m]=0.f; }
  const float* w = pw2 + (size_t)k0*H_ + col;
  #pragma unroll 4
  for (int kk=0; kk<KC2; kk++){
    float w0 = w[0], w1 = w[256];
    w += H_;
    #pragma unroll
    for (int m=0;m<16;m++){
      float x = xs[kk*16+m];
      a0[m] = fmaf(x, w0, a0[m]);
      a1[m] = fmaf(x, w1, a1[m]);
    }
  }
  float* o = p2 + (size_t)ks*B_*H_ + col;
  #pragma unroll
  for (int m=0;m<16;m++){ o[(size_t)m*H_] = a0[m]; o[(size_t)m*H_ + 256] = a1[m]; }
}

// reduce logits, gumbel-argmax sample, write one-hot into fulls, post log-softmax, idx
__global__ __launch_bounds__(256) void sample_kernel(const float* __restrict__ p2,
    const float* __restrict__ pb2, const float* __restrict__ gum, int t,
    float* __restrict__ dout, int* __restrict__ idxb){
  int b = blockIdx.x, tid = threadIdx.x;
  __shared__ float lg[1024];
  for (int c = tid; c < 1024; c += 256){
    float v = pb2[c];
    #pragma unroll
    for (int s=0;s<KS2;s++) v += p2[((size_t)s*B_ + b)*H_ + c];
    lg[c] = v;
  }
  __syncthreads();
  int lane = tid & 31;
  int grp = tid >> 5;    // 8 groups of 32 lanes
  size_t bt = (size_t)b*T_ + t;
  for (int rep=0; rep<4; rep++){
    int nc = rep*8 + grp;
    float l = lg[nc*32 + lane];
    float g = gum[((size_t)t << 14) + (size_t)b*1024 + nc*32 + lane];
    float y = l + g;
    int widx = lane; float wy = y;
    #pragma unroll
    for (int off=16; off>0; off>>=1){
      float oy = __shfl_xor(wy, off, 32);
      int   oi = __shfl_xor(widx, off, 32);
      if (oy > wy || (oy == wy && oi < widx)){ wy = oy; widx = oi; }
    }
    float mx = l;
    #pragma unroll
    for (int off=16; off>0; off>>=1) mx = fmaxf(mx, __shfl_xor(mx, off, 32));
    float e = expf(l - mx);
    float s = e;
    #pragma unroll
    for (int off=16; off>0; off>>=1) s += __shfl_xor(s, off, 32);
    float ls = logf(s);
    dout[POST0 + (bt*NC_ + nc)*NK_ + lane] = (l - mx) - ls;
    dout[FULLS0 + bt*FULL_ + R_ + nc*32 + lane] = (lane == widx) ? 1.0f : 0.0f;
    if (lane == 0) idxb[b*32 + nc] = widx;
  }
}

// fused GRU GEMMs: gx partials (h-part streamed; latent one-hot gathered; act rows)
// and gh partials. Grid: 384 gx blocks + 192 gh blocks.
__global__ __launch_bounds__(256) void gru_gemms(const float* __restrict__ gwih,
    const float* __restrict__ gwhh, const float* __restrict__ h,
    const int* __restrict__ idxb, const float* __restrict__ act, int t,
    float* __restrict__ pgx, float* __restrict__ pgh){
  __shared__ float xs[KCG*16];       // 16 KB max
  __shared__ float as_[16*18];
  __shared__ int idxs[512];
  int bid = blockIdx.x, tid = threadIdx.x;
  if (bid < 384){
    int n = bid / 48, r = bid % 48, ct = r / 16, ks = r % 16;
    int col = ct*512 + tid;
    int k0 = ks*KCG;
    for (int i = tid; i < KCG*16; i += 256){
      int kk = i >> 4, m = i & 15;
      xs[i] = h[m*R_ + k0 + kk];
    }
    if (ks == 0){
      for (int i = tid; i < 16*18; i += 256){
        int m = i/18, a = i%18;
        as_[i] = act[((m*T_)+t)*A_ + a];
      }
      for (int i = tid; i < 512; i += 256) idxs[i] = idxb[i];
    }
    __syncthreads();
    float a0[16], a1[16];
    #pragma unroll
    for (int m=0;m<16;m++){ a0[m]=0.f; a1[m]=0.f; }
    const float* wbase = gwih + (size_t)n*GIN_*G3_ + col;
    const float* w = wbase + (size_t)k0*G3_;
    #pragma unroll 4
    for (int kk=0; kk<KCG; kk++){
      float w0 = w[0], w1 = w[256];
      w += G3_;
      #pragma unroll
      for (int m=0;m<16;m++){
        float x = xs[kk*16+m];
        a0[m] = fmaf(x, w0, a0[m]);
        a1[m] = fmaf(x, w1, a1[m]);
      }
    }
    if (ks == 0){
      // latent: one-hot gather of 32 rows per batch element
      for (int nc=0; nc<32; nc++){
        #pragma unroll
        for (int m=0;m<16;m++){
          size_t row = (size_t)(R_ + nc*32 + idxs[m*32+nc]);
          a0[m] += wbase[row*G3_];
          a1[m] += wbase[row*G3_ + 256];
        }
      }
      // action rows (18)
      for (int a=0; a<18; a++){
        float w0 = wbase[(size_t)(R_+LAT_+a)*G3_];
        float w1 = wbase[(size_t)(R_+LAT_+a)*G3_ + 256];
        #pragma unroll
        for (int m=0;m<16;m++){
          float x = as_[m*18+a];
          a0[m] = fmaf(x, w0, a0[m]);
          a1[m] = fmaf(x, w1, a1[m]);
        }
      }
    }
    float* o = pgx + (size_t)ks*B_*NG_ + (size_t)n*G3_ + col;
    #pragma unroll
    for (int m=0;m<16;m++){ o[(size_t)m*NG_] = a0[m]; o[(size_t)m*NG_ + 256] = a1[m]; }
  } else {
    int b2 = bid - 384;
    int n = b2 / 24, r = b2 % 24, ct = r / 8, ks = r % 8;
    int col = ct*512 + tid;
    int k0 = ks*KCH;
    for (int i = tid; i < KCH*16; i += 256){
      int kk = i >> 4, m = i & 15;
      xs[i] = h[m*R_ + n*BS_ + k0 + kk];
    }
    __syncthreads();
    float a0[16], a1[16];
    #pragma unroll
    for (int m=0;m<16;m++){ a0[m]=0.f; a1[m]=0.f; }
    const float* w = gwhh + (size_t)n*BS_*G3_ + (size_t)k0*G3_ + col;
    #pragma unroll 4
    for (int kk=0; kk<KCH; kk++){
      float w0 = w[0], w1 = w[256];
      w += G3_;
      #pragma unroll
      for (int m=0;m<16;m++){
        float x = xs[kk*16+m];
        a0[m] = fmaf(x, w0, a0[m]);
        a1[m] = fmaf(x, w1, a1[m]);
      }
    }
    float* o = pgh + (size_t)ks*B_*NG_ + (size_t)n*G3_ + col;
    #pragma unroll
    for (int m=0;m<16;m++){ o[(size_t)m*NG_] = a0[m]; o[(size_t)m*NG_ + 256] = a1[m]; }
  }
}

// reduce gx/gh partials, apply GRU gates, update h, write h_t into recs & fulls
__global__ __launch_bounds__(256) void gate_kernel(const float* __restrict__ pgx,
    const float* __restrict__ pgh, const float* __restrict__ gbih,
    const float* __restrict__ gbhh, const float* __restrict__ h_old,
    float* __restrict__ h_new, const int* __restrict__ dones, int t,
    float* __restrict__ dout){
  int g = blockIdx.x*256 + threadIdx.x;  // 65536
  int b = g >> 12, j = g & 4095;
  int n = j >> 9, u = j & 511;
  float rx = gbih[n*G3_ + u], zx = gbih[n*G3_ + 512 + u], nx = gbih[n*G3_ + 1024 + u];
  #pragma unroll
  for (int s=0;s<KSG;s++){
    const float* p = pgx + ((size_t)s*B_ + b)*NG_ + (size_t)n*G3_;
    rx += p[u]; zx += p[512+u]; nx += p[1024+u];
  }
  float rh = gbhh[n*G3_ + u], zh = gbhh[n*G3_ + 512 + u], nh = gbhh[n*G3_ + 1024 + u];
  #pragma unroll
  for (int s=0;s<KSH;s++){
    const float* p = pgh + ((size_t)s*B_ + b)*NG_ + (size_t)n*G3_;
    rh += p[u]; zh += p[512+u]; nh += p[1024+u];
  }
  float rr = 1.f/(1.f + expf(-(rx+rh)));
  float zz = 1.f/(1.f + expf(-(zx+zh)));
  float nn = tanhf(nx + rr*nh);
  float hold = h_old[g];
  float hnew = (1.f - zz)*nn + zz*hold;
  float nd = 1.f - (float)dones[b*T_ + t];
  h_new[g] = hnew * nd;
  size_t bt = (size_t)b*T_ + t;
  dout[FULLS0 + bt*FULL_ + j] = hold;
  dout[RECS0 + bt*(size_t)R_ + j] = hold;
}

// ---------------- prior MLP (batch GEMM at end) ----------------
template<int ACT>
__global__ __launch_bounds__(256) void gemm_tiled(const float* __restrict__ Aa,
    const float* __restrict__ W, const float* __restrict__ bias,
    float* __restrict__ out, int M, int N, int K){
  __shared__ float As[16][68];   // padded: conflict-free writes
  __shared__ float Bs[16][64];
  int bx = blockIdx.x, by = blockIdx.y, tid = threadIdx.x;
  int tx = tid & 15, ty = tid >> 4;
  int n0 = bx*64, m0 = by*64;
  float acc[4][4];
  #pragma unroll
  for (int i=0;i<4;i++)
    #pragma unroll
    for (int j=0;j<4;j++) acc[i][j] = 0.f;
  for (int k0=0; k0<K; k0+=16){
    #pragma unroll
    for (int p=0;p<4;p++){
      int idx = tid + p*256;
      int kk = idx & 15, mm = idx >> 4;
      As[kk][mm] = Aa[(size_t)(m0+mm)*K + k0 + kk];
      int kk2 = idx >> 6, nn2 = idx & 63;
      Bs[kk2][nn2] = W[(size_t)(k0+kk2)*N + n0 + nn2];
    }
    __syncthreads();
    #pragma unroll
    for (int kk=0;kk<16;kk++){
      float a[4], bb[4];
      #pragma unroll
      for (int i=0;i<4;i++) a[i] = As[kk][ty*4+i];
      #pragma unroll
      for (int j=0;j<4;j++) bb[j] = Bs[kk][tx*4+j];
      #pragma unroll
      for (int i=0;i<4;i++)
        #pragma unroll
        for (int j=0;j<4;j++) acc[i][j] = fmaf(a[i], bb[j], acc[i][j]);
    }
    __syncthreads();
  }
  #pragma unroll
  for (int i=0;i<4;i++){
    #pragma unroll
    for (int j=0;j<4;j++){
      int mm = m0 + ty*4 + i, nn = n0 + tx*4 + j;
      float v = acc[i][j] + bias[nn];
      if (ACT){ float sg = 1.f/(1.f + expf(-v)); v = v*sg; }
      out[(size_t)mm*N + nn] = v;
    }
  }
}

__global__ __launch_bounds__(256) void logsoftmax_kernel(float* __restrict__ x){
  int g = blockIdx.x*256 + threadIdx.x;
  float v = x[g];
  float mx = v;
  #pragma unroll
  for (int off=16; off>0; off>>=1) mx = fmaxf(mx, __shfl_xor(mx, off, 32));
  float e = expf(v - mx);
  float s = e;
  #pragma unroll
  for (int off=16; off>0; off>>=1) s += __shfl_xor(s, off, 32);
  x[g] = (v - mx) - logf(s);
}

// ---------------- launch ----------------
extern "C" void kernel_launch(void* const* d_in, const int* in_sizes, int n_in,
                              void* d_out, int out_size, void* d_ws, size_t ws_size,
                              hipStream_t stream){
  const float* obs  = (const float*)d_in[0];
  const float* act  = (const float*)d_in[1];
  const int*   dons = (const int*)d_in[2];
  const float* pw1  = (const float*)d_in[3];
  const float* pb1  = (const float*)d_in[4];
  const float* pw2  = (const float*)d_in[5];
  const float* pb2  = (const float*)d_in[6];
  const float* qw1  = (const float*)d_in[7];
  const float* qb1  = (const float*)d_in[8];
  const float* qw2  = (const float*)d_in[9];
  const float* qb2  = (const float*)d_in[10];
  const float* gwih = (const float*)d_in[11];
  const float* gwhh = (const float*)d_in[12];
  const float* gbih = (const float*)d_in[13];
  const float* gbhh = (const float*)d_in[14];
  float* out = (float*)d_out;
  float* ws  = (float*)d_ws;

  size_t off = 0;
  float* gum    = ws + off; off += (size_t)T_*B_*NC_*NK_;     // 1048576
  float* h0     = ws + off; off += (size_t)B_*R_;             // 65536
  float* h1     = ws + off; off += (size_t)B_*R_;
  float* hidden = ws + off; off += (size_t)B_*H_;
  float* p1     = ws + off; off += (size_t)KS1*B_*H_;         // 1048576
  float* p2     = ws + off; off += (size_t)KS2*B_*H_;         // 524288
  float* pgx    = ws + off; off += (size_t)KSG*B_*NG_;        // 3145728
  float* pgh    = ws + off; off += (size_t)KSH*B_*NG_;        // 1572864
  float* hidp   = ws + off; off += (size_t)H_*B_*T_;          // 1048576
  int*   idxb   = (int*)(ws + off);

  gumbel_init<<<(T_*B_*NC_*NK_)/256, 256, 0, stream>>>(gum);
  hipMemsetAsync(h0, 0, (size_t)B_*R_*sizeof(float), stream);

  float* hcur = h0; float* hnxt = h1;
  for (int t=0; t<T_; t++){
    mlp1_gemv<<<dim3(2, KS1), 256, 0, stream>>>(pw1, hcur, obs, t, p1);
    mlp1_reduce<<<(B_*H_)/256, 256, 0, stream>>>(p1, pb1, hidden);
    mlp2_gemv<<<dim3(2, KS2), 256, 0, stream>>>(pw2, hidden, p2);
    sample_kernel<<<B_, 256, 0, stream>>>(p2, pb2, gum, t, out, idxb);
    gru_gemms<<<576, 256, 0, stream>>>(gwih, gwhh, hcur, idxb, act, t, pgx, pgh);
    gate_kernel<<<(B_*R_)/256, 256, 0, stream>>>(pgx, pgh, gbih, gbhh, hcur, hnxt, dons, t, out);
    float* tmp = hcur; hcur = hnxt; hnxt = tmp;
  }

  gemm_tiled<1><<<dim3(16,16), 256, 0, stream>>>(out + RECS0, qw1, qb1, hidp, 1024, 1024, 4096);
  gemm_tiled<0><<<dim3(16,16), 256, 0, stream>>>(hidp, qw2, qb2, out + PRIOR0, 1024, 1024, 1024);
  logsoftmax_kernel<<<(B_*T_*LAT_)/256, 256, 0, stream>>>(out + PRIOR0);
}